// Round 1
// 249.884 us; speedup vs baseline: 1.0015x; 1.0015x over previous
//
#include <hip/hip_runtime.h>
#include <hip/hip_bf16.h>

#define NN 50000
#define NE 1600000
#define DD 128
#define NB 196        // 256-node bins: ceil(50000/256)
#define NCH 256       // edge chunks
#define PER 6250      // NE / NCH
#define NT 4          // src tiles
#define TS 12500      // nodes per src tile

typedef short bfrag __attribute__((ext_vector_type(8)));   // 8 bf16 = 4 VGPR
typedef float ffrag __attribute__((ext_vector_type(4)));   // 4 f32 acc
typedef float f32x2 __attribute__((ext_vector_type(2)));   // packed f32 pair

__device__ __forceinline__ float bf2f(unsigned short u) {
    union { unsigned int i; float f; } c; c.i = ((unsigned int)u) << 16; return c.f;
}
__device__ __forceinline__ unsigned short f2bf(float f) {
    __hip_bfloat16 h = __float2bfloat16(f);
    union { __hip_bfloat16 h; unsigned short u; } c; c.h = h; return c.u;
}
__device__ __forceinline__ int insane_bf16(unsigned short u) {
    unsigned e = (u >> 7) & 0xFF;
    return (e == 0xFF) || (e >= 0x8E);
}

// flags[0]=indices int64; flags[1]=feat f32 (=> out f32); flags[2]=W f32
__global__ void k_detect(const int* __restrict__ srcw, const int* __restrict__ dstw,
                         const unsigned short* __restrict__ feat16,
                         const unsigned short* __restrict__ w16,
                         int* __restrict__ flags) {
    __shared__ int s_idx, s_feat, s_w;
    int tid = threadIdx.x;
    if (tid == 0) { s_idx = 0; s_feat = 0; s_w = 0; }
    __syncthreads();
    if (tid < 64) {
        int v = srcw[2 * tid + 1] | dstw[2 * tid + 1];
        if (v) atomicOr(&s_idx, 1);
    }
    if (insane_bf16(feat16[2 * tid]) || insane_bf16(feat16[2 * tid + 512]))
        atomicOr(&s_feat, 1);
    if (insane_bf16(w16[2 * tid]) || insane_bf16(w16[2 * tid + 512]))
        atomicOr(&s_w, 1);
    __syncthreads();
    if (tid == 0) { flags[0] = (s_idx == 0) ? 1 : 0; flags[1] = s_feat; flags[2] = s_w; }
}

__device__ __forceinline__ int load_idx(const void* p, int e, int is64) {
    long long v = is64 ? ((const long long*)p)[e] : (long long)((const int*)p)[e];
    int i = (int)v;
    return (i < 0) ? 0 : (i >= NN ? NN - 1 : i);
}

// chunk-block counts its edges per bin
__global__ __launch_bounds__(256) void k_count(const void* __restrict__ dst,
        int* __restrict__ cnt, const int* __restrict__ flags) {
    __shared__ int lc[NB];
    int c = blockIdx.x, tid = threadIdx.x;
    if (tid < NB) lc[tid] = 0;
    __syncthreads();
    int lo = c * PER, hi = lo + PER; if (hi > NE) hi = NE;
    int is64 = flags[0];
    for (int e = lo + tid; e < hi; e += 256)
        atomicAdd(&lc[load_idx(dst, e, is64) >> 8], 1);
    __syncthreads();
    if (tid < NB) cnt[tid * NCH + c] = lc[tid];
}

// per-bin exclusive scan over chunks
__global__ __launch_bounds__(256) void k_scan2(const int* __restrict__ cnt,
        int* __restrict__ loff, int* __restrict__ binsum) {
    __shared__ int buf[256];
    int b = blockIdx.x, tid = threadIdx.x;
    int v = cnt[b * NCH + tid];
    buf[tid] = v;
    __syncthreads();
    for (int off = 1; off < 256; off <<= 1) {
        int t = (tid >= off) ? buf[tid - off] : 0;
        __syncthreads();
        buf[tid] += t;
        __syncthreads();
    }
    loff[b * NCH + tid] = buf[tid] - v;
    if (tid == 255) binsum[b] = buf[255];
}

// scan bin totals -> binoff[0..NB]; rowptr[NN]=NE
__global__ __launch_bounds__(256) void k_scanbin(const int* __restrict__ binsum,
        int* __restrict__ binoff, int* __restrict__ rowptr) {
    __shared__ int buf[256];
    int tid = threadIdx.x;
    int v = (tid < NB) ? binsum[tid] : 0;
    buf[tid] = v;
    __syncthreads();
    for (int off = 1; off < 256; off <<= 1) {
        int t = (tid >= off) ? buf[tid - off] : 0;
        __syncthreads();
        buf[tid] += t;
        __syncthreads();
    }
    if (tid < NB) binoff[tid] = buf[tid] - v;
    if (tid == NB - 1) binoff[NB] = buf[tid];
    if (tid == 0) rowptr[NN] = NE;
}

// chunk-block places edges into bin-major staged[] via precomputed offsets
__global__ __launch_bounds__(256) void k_stage(const void* __restrict__ src,
        const void* __restrict__ dst, const int* __restrict__ binoff,
        const int* __restrict__ loff, unsigned* __restrict__ staged,
        const int* __restrict__ flags) {
    __shared__ int cur[NB];
    int c = blockIdx.x, tid = threadIdx.x;
    if (tid < NB) cur[tid] = binoff[tid] + loff[tid * NCH + c];
    __syncthreads();
    int lo = c * PER, hi = lo + PER; if (hi > NE) hi = NE;
    int is64 = flags[0];
    for (int e = lo + tid; e < hi; e += 256) {
        int d = load_idx(dst, e, is64);
        int s = load_idx(src, e, is64);
        int pos = atomicAdd(&cur[d >> 8], 1);
        staged[pos] = ((unsigned)(d & 255) << 16) | (unsigned)s;
    }
}

// bin-block: (node,tile) LDS count -> scan -> rowptr/norm -> tile-grouped scatter
__global__ __launch_bounds__(512) void k_fill(const unsigned* __restrict__ staged,
        const int* __restrict__ binoff, int* __restrict__ rowptr,
        float* __restrict__ norm, int* __restrict__ srclist) {
    __shared__ int cnt4[256 * NT];
    __shared__ int ntot[256];
    int b = blockIdx.x, tid = threadIdx.x;
    int lo = binoff[b], hi = binoff[b + 1];
    for (int i = tid; i < 256 * NT; i += 512) cnt4[i] = 0;
    __syncthreads();
    for (int k = lo + tid; k < hi; k += 512) {
        unsigned u = staged[k];
        atomicAdd(&cnt4[(u >> 16) * NT + (int)(u & 0xffff) / TS], 1);
    }
    __syncthreads();
    if (tid < 256)
        ntot[tid] = cnt4[tid * NT] + cnt4[tid * NT + 1]
                  + cnt4[tid * NT + 2] + cnt4[tid * NT + 3];
    __syncthreads();
    for (int off = 1; off < 256; off <<= 1) {
        int t = 0;
        if (tid < 256 && tid >= off) t = ntot[tid - off];
        __syncthreads();
        if (tid < 256) ntot[tid] += t;
        __syncthreads();
    }
    if (tid < 256) {
        int v0 = cnt4[tid * NT], v1 = cnt4[tid * NT + 1];
        int v2 = cnt4[tid * NT + 2], v3 = cnt4[tid * NT + 3];
        int deg = v0 + v1 + v2 + v3;
        int start = lo + ntot[tid] - deg;
        int n = b * 256 + tid;
        if (n < NN) {
            rowptr[n] = start;
            norm[n] = rsqrtf(fmaxf((float)deg, 1.0f));
        }
        int c = start;
        cnt4[tid * NT + 0] = c; c += v0;
        cnt4[tid * NT + 1] = c; c += v1;
        cnt4[tid * NT + 2] = c; c += v2;
        cnt4[tid * NT + 3] = c;
    }
    __syncthreads();
    for (int k = lo + tid; k < hi; k += 512) {
        unsigned u = staged[k];
        int pos = atomicAdd(&cnt4[(u >> 16) * NT + (int)(u & 0xffff) / TS], 1);
        srclist[pos] = (int)(u & 0xffff);
    }
}

// X1[n,d] = feat[n,d] * norm[n]  (bf16)
__global__ void k_prescale(const void* __restrict__ feat,
                           const float* __restrict__ norm,
                           unsigned short* __restrict__ X,
                           const int* __restrict__ flags) {
    int i = blockIdx.x * 256 + threadIdx.x;
    if (i >= NN * DD / 4) return;
    float nm = norm[i >> 5];
    float4 v;
    if (flags[1]) {
        v = ((const float4*)feat)[i];
    } else {
        ushort4 f = ((const ushort4*)feat)[i];
        v.x = bf2f(f.x); v.y = bf2f(f.y); v.z = bf2f(f.z); v.w = bf2f(f.w);
    }
    ushort4 o;
    o.x = f2bf(v.x * nm); o.y = f2bf(v.y * nm);
    o.z = f2bf(v.z * nm); o.w = f2bf(v.w * nm);
    ((ushort4*)X)[i] = o;
}

// packed bf16-pair -> f32x2 (1 shift + 1 and), accumulate via v_pk_add_f32
__device__ __forceinline__ f32x2 bfpair(unsigned u) {
    union { unsigned i; float f; } lo, hi;
    lo.i = u << 16;
    hi.i = u & 0xffff0000u;
    f32x2 r; r[0] = lo.f; r[1] = hi.f; return r;
}
__device__ __forceinline__ void accp(f32x2* a, uint4 v) {
    a[0] += bfpair(v.x);
    a[1] += bfpair(v.y);
    a[2] += bfpair(v.z);
    a[3] += bfpair(v.w);
}

// gather-reduce: one wave per dst node; 4 edge-slots x 16 lanes x 16B rows.
// Software-pipelined one stage deep: while accumulating the current 4 rows,
// the next 4 srclist entries + 4 row loads are already in flight (8 rows
// outstanding during the VALU burst). Accumulation is f32x2 (v_pk_add_f32).
// mode 0: out = bf16(acc * norm^2) -> X2;  mode 1: out = bf16(acc * norm) -> Yb
__global__ __launch_bounds__(256, 6) void k_gather(const unsigned short* __restrict__ Xin,
        const int* __restrict__ rowptr, const int* __restrict__ srclist,
        const float* __restrict__ norm, unsigned short* __restrict__ outp,
        int mode) {
    int wid = (blockIdx.x * 256 + threadIdx.x) >> 6;
    int lane = threadIdx.x & 63;
    if (wid >= NN) return;
    int beg = rowptr[wid], end = rowptr[wid + 1];
    int g = lane >> 4;
    int c8 = (lane & 15) << 3;
    const unsigned short* xb = Xin + c8;
    f32x2 a[4];
    #pragma unroll
    for (int k = 0; k < 4; ++k) a[k] = (f32x2){0.f, 0.f};

    int j = beg + g;
    uint4 r0, r1, r2, r3;
    bool cur = (j + 12 < end);
    if (cur) {
        int s0 = srclist[j];
        int s1 = srclist[j + 4];
        int s2 = srclist[j + 8];
        int s3 = srclist[j + 12];
        r0 = *(const uint4*)(xb + s0 * DD);
        r1 = *(const uint4*)(xb + s1 * DD);
        r2 = *(const uint4*)(xb + s2 * DD);
        r3 = *(const uint4*)(xb + s3 * DD);
        j += 16;
    }
    while (cur) {
        bool nxt = (j + 12 < end);
        uint4 n0, n1, n2, n3;
        if (nxt) {
            int s0 = srclist[j];
            int s1 = srclist[j + 4];
            int s2 = srclist[j + 8];
            int s3 = srclist[j + 12];
            n0 = *(const uint4*)(xb + s0 * DD);
            n1 = *(const uint4*)(xb + s1 * DD);
            n2 = *(const uint4*)(xb + s2 * DD);
            n3 = *(const uint4*)(xb + s3 * DD);
            j += 16;
        }
        accp(a, r0); accp(a, r1); accp(a, r2); accp(a, r3);
        r0 = n0; r1 = n1; r2 = n2; r3 = n3;
        cur = nxt;
    }
    for (; j < end; j += 4) {
        int s = srclist[j];
        uint4 v = *(const uint4*)(xb + s * DD);
        accp(a, v);
    }
    #pragma unroll
    for (int k = 0; k < 4; ++k) {
        a[k][0] += __shfl_xor(a[k][0], 16);
        a[k][1] += __shfl_xor(a[k][1], 16);
        a[k][0] += __shfl_xor(a[k][0], 32);
        a[k][1] += __shfl_xor(a[k][1], 32);
    }

    if (g == 0) {
        float nm = norm[wid];
        float sc = (mode == 0) ? nm * nm : nm;
        uint4 o;
        o.x = ((unsigned)f2bf(a[0][1] * sc) << 16) | (unsigned)f2bf(a[0][0] * sc);
        o.y = ((unsigned)f2bf(a[1][1] * sc) << 16) | (unsigned)f2bf(a[1][0] * sc);
        o.z = ((unsigned)f2bf(a[2][1] * sc) << 16) | (unsigned)f2bf(a[2][0] * sc);
        o.w = ((unsigned)f2bf(a[3][1] * sc) << 16) | (unsigned)f2bf(a[3][0] * sc);
        *(uint4*)(outp + wid * DD + c8) = o;
    }
}

// MFMA GEMM: out[n,o] = Yb[n,:] @ W[o,:] + b[o].  Yb bf16 (norm applied).
__global__ __launch_bounds__(256) void k_gemm2(const unsigned short* __restrict__ Yb,
        const void* __restrict__ Wp, const void* __restrict__ bp,
        void* __restrict__ outp, const int* __restrict__ flags) {
    __shared__ unsigned short Wl[DD * 136];
    int tid = threadIdx.x;
    int wf32 = flags[2], of32 = flags[1];

    for (int i = tid; i < 8192; i += 256) {
        int r = i >> 6, cc = i & 63;
        unsigned pk;
        if (wf32) {
            float2 w = ((const float2*)Wp)[i];
            pk = ((unsigned)f2bf(w.y) << 16) | (unsigned)f2bf(w.x);
        } else {
            pk = ((const unsigned*)Wp)[i];
        }
        *(unsigned*)&Wl[r * 136 + cc * 2] = pk;
    }
    __syncthreads();

    int wave = tid >> 6, lane = tid & 63;
    int nb = blockIdx.x * 64 + wave * 16;
    int m = lane & 15, quad = lane >> 4;
    int arow = nb + m; if (arow >= NN) arow = NN - 1;
    const unsigned short* arp = Yb + arow * DD + quad * 8;

    ffrag acc[8];
    #pragma unroll
    for (int t = 0; t < 8; ++t) acc[t] = (ffrag){0.f, 0.f, 0.f, 0.f};

    #pragma unroll
    for (int c = 0; c < 4; ++c) {
        bfrag af = *(const bfrag*)(arp + c * 32);
        #pragma unroll
        for (int t = 0; t < 8; ++t) {
            bfrag bf = *(const bfrag*)&Wl[(t * 16 + m) * 136 + c * 32 + quad * 8];
            acc[t] = __builtin_amdgcn_mfma_f32_16x16x32_bf16(af, bf, acc[t], 0, 0, 0);
        }
    }

    #pragma unroll
    for (int t = 0; t < 8; ++t) {
        int o = t * 16 + m;
        float bias = wf32 ? ((const float*)bp)[o] : bf2f(((const unsigned short*)bp)[o]);
        #pragma unroll
        for (int r = 0; r < 4; ++r) {
            int n = nb + quad * 4 + r;
            if (n < NN) {
                float v = acc[t][r] + bias;
                if (of32) ((float*)outp)[n * DD + o] = v;
                else      ((unsigned short*)outp)[n * DD + o] = f2bf(v);
            }
        }
    }
}

extern "C" void kernel_launch(void* const* d_in, const int* in_sizes, int n_in,
                              void* d_out, int out_size, void* d_ws, size_t ws_size,
                              hipStream_t stream) {
    const void* feat = d_in[0];
    const void* src  = d_in[1];
    const void* dst  = d_in[2];
    const void* W    = d_in[3];
    const void* b    = d_in[4];

    // ws (bytes): flags@0 | rowptr@64 | norm@200128 | cnt@400128 | loff@600832 |
    //   binsum@801536 | binoff@802560 | srclist@803584 | X1@7203584 | X2@20003584
    //   staged aliases X2's first 6.4MB (dead before gather-0 writes X2). end 32.8MB
    char* wsb = (char*)d_ws;
    int*   flags   = (int*)wsb;
    int*   rowptr  = (int*)(wsb + 64);
    float* norm    = (float*)(wsb + 200128);
    int*   cnt     = (int*)(wsb + 400128);
    int*   loff    = (int*)(wsb + 600832);
    int*   binsum  = (int*)(wsb + 801536);
    int*   binoff  = (int*)(wsb + 802560);
    int*   srclist = (int*)(wsb + 803584);
    unsigned short* X1 = (unsigned short*)(wsb + 7203584);   // hop-1 input, then Yb
    unsigned short* X2 = (unsigned short*)(wsb + 20003584);
    unsigned* staged   = (unsigned*)(wsb + 20003584);

    k_detect<<<1, 256, 0, stream>>>((const int*)src, (const int*)dst,
                                    (const unsigned short*)feat,
                                    (const unsigned short*)W, flags);
    k_count<<<NCH, 256, 0, stream>>>(dst, cnt, flags);
    k_scan2<<<NB, 256, 0, stream>>>(cnt, loff, binsum);
    k_scanbin<<<1, 256, 0, stream>>>(binsum, binoff, rowptr);
    k_stage<<<NCH, 256, 0, stream>>>(src, dst, binoff, loff, staged, flags);
    k_fill<<<NB, 512, 0, stream>>>(staged, binoff, rowptr, norm, srclist);
    k_prescale<<<(NN * DD / 4 + 255) / 256, 256, 0, stream>>>(feat, norm, X1, flags);
    k_gather<<<(NN + 3) / 4, 256, 0, stream>>>(X1, rowptr, srclist, norm, X2, 0);
    k_gather<<<(NN + 3) / 4, 256, 0, stream>>>(X2, rowptr, srclist, norm, X1, 1);
    k_gemm2<<<(NN + 63) / 64, 256, 0, stream>>>(X1, W, b, d_out, flags);
}